// Round 7
// baseline (149.348 us; speedup 1.0000x reference)
//
#include <hip/hip_runtime.h>
#include <math.h>

#define EPSN 1e-4f
#define SEQ 2304

using bf16x8 = __attribute__((ext_vector_type(8))) short;
using f32x4  = __attribute__((ext_vector_type(4))) float;

__device__ inline unsigned short f2bf(float x) {
    union { float f; unsigned u; } c; c.f = x;
    unsigned u = c.u;
    u += 0x7fffu + ((u >> 16) & 1u);
    return (unsigned short)(u >> 16);
}

// ---------------- Kernel 1: prep = weight-norm (blocks 0..1023) + x-transpose ----------------
__global__ __launch_bounds__(256) void prep_kernel(const float* __restrict__ w_qkv,
                                                   const float* __restrict__ w_out,
                                                   const float* __restrict__ x,
                                                   unsigned short* __restrict__ wqb,
                                                   unsigned short* __restrict__ wob,
                                                   unsigned short* __restrict__ xt) {
    __shared__ __align__(16) unsigned short T[64][80];
    __shared__ float red[4];
    __shared__ float scale_s;
    int bid = blockIdx.x;
    if (bid < 1024) {
        const float* src;
        unsigned short* dst;
        if (bid < 768) { src = w_qkv + bid * 256; dst = wqb + bid * 256; }
        else           { src = w_out + (bid - 768) * 256; dst = wob + (bid - 768) * 256; }
        float v = src[threadIdx.x];
        float ss = v * v;
        for (int off = 32; off > 0; off >>= 1) ss += __shfl_down(ss, off, 64);
        int lane = threadIdx.x & 63, wid = threadIdx.x >> 6;
        if (lane == 0) red[wid] = ss;
        __syncthreads();
        if (threadIdx.x == 0) {
            float t = red[0] + red[1] + red[2] + red[3];
            scale_s = 1.0f / (sqrtf(t) + 16.0f * EPSN);
        }
        __syncthreads();
        dst[threadIdx.x] = f2bf(v * scale_s);
    } else {
        int e0 = bid - 1024;           // 0..287
        int st = e0 % 36, ct = (e0 / 36) & 3, n = e0 / 144;
        int t = threadIdx.x;
#pragma unroll
        for (int p = 0; p < 4; ++p) {
            int e = t + p * 256;
            int c = e >> 4, sv = (e & 15) * 4;
            float4 v = *(const float4*)&x[(size_t)(n * 256 + ct * 64 + c) * SEQ + st * 64 + sv];
            T[sv + 0][c] = f2bf(v.x);
            T[sv + 1][c] = f2bf(v.y);
            T[sv + 2][c] = f2bf(v.z);
            T[sv + 3][c] = f2bf(v.w);
        }
        __syncthreads();
#pragma unroll
        for (int p = 0; p < 2; ++p) {
            int e = t + p * 256;
            int s = e >> 3, cb = (e & 7) * 8;
            uint4 v = *(const uint4*)&T[s][cb];
            *(uint4*)&xt[(size_t)(n * SEQ + st * 64 + s) * 256 + ct * 64 + cb] = v;
        }
    }
}

// ---------------- Kernel 2: fused QKV GEMM + d-normalize (unchanged, proven) ----------------
__global__ __launch_bounds__(256) void qkv_fused_kernel(const unsigned short* __restrict__ xt,
                                                        const unsigned short* __restrict__ wqb,
                                                        unsigned short* __restrict__ qn,
                                                        unsigned short* __restrict__ kn,
                                                        unsigned short* __restrict__ vn) {
    __shared__ __align__(16) char smem[96 * 65 * 4];
    float (*Cs)[65] = (float(*)[65])smem;
    int h  = blockIdx.x;
    int st = blockIdx.y;
    int n  = blockIdx.z;
    int tid = threadIdx.x;
    int wave = tid >> 6, lane = tid & 63;
    int ln = lane & 15, quad = lane >> 4;
    const unsigned short* Abase = wqb + (size_t)(h * 96 + ln) * 256 + quad * 8;
    const unsigned short* Bbase = xt + (size_t)(n * SEQ + st * 64 + wave * 16 + ln) * 256 + quad * 8;
    f32x4 acc[6];
#pragma unroll
    for (int m = 0; m < 6; ++m) acc[m] = (f32x4){0.f, 0.f, 0.f, 0.f};
#pragma unroll
    for (int kc = 0; kc < 8; ++kc) {
        bf16x8 b = *(const bf16x8*)(Bbase + kc * 32);
#pragma unroll
        for (int m = 0; m < 6; ++m) {
            bf16x8 a = *(const bf16x8*)(Abase + (size_t)(m * 16) * 256 + kc * 32);
            acc[m] = __builtin_amdgcn_mfma_f32_16x16x32_bf16(a, b, acc[m], 0, 0, 0);
        }
    }
#pragma unroll
    for (int m = 0; m < 6; ++m)
#pragma unroll
        for (int r = 0; r < 4; ++r)
            Cs[m * 16 + quad * 4 + r][wave * 16 + ln] = acc[m][r];
    __syncthreads();
    int sl = tid & 63, wh = tid >> 6;
    float v[32];
    float inv = 0.f;
    if (tid < 192) {
        float ss = 0.f;
#pragma unroll
        for (int d = 0; d < 32; ++d) { v[d] = Cs[3 * d + wh][sl]; ss += v[d] * v[d]; }
        inv = 1.0f / (EPSN + sqrtf(ss * (1.0f / 32.0f)));
        if (wh == 0) inv *= 0.2550348660352446f;   // (1/sqrt(32)) * log2(e): exp2 softmax
    }
    __syncthreads();
    unsigned short (*Sq)[40] = (unsigned short(*)[40])smem;
    unsigned short (*Sk)[40] = (unsigned short(*)[40])(smem + 5120);
    unsigned short (*Sv)[72] = (unsigned short(*)[72])(smem + 10240);
    if (tid < 192) {
        if (wh == 2) {
#pragma unroll
            for (int d = 0; d < 32; ++d) Sv[d][sl] = f2bf(v[d] * inv);
        } else {
            unsigned short (*S)[40] = wh ? Sk : Sq;
#pragma unroll
            for (int j = 0; j < 16; ++j) {
                unsigned p = (unsigned)f2bf(v[2 * j] * inv) | ((unsigned)f2bf(v[2 * j + 1] * inv) << 16);
                *(unsigned*)&S[sl][2 * j] = p;
            }
        }
    }
    __syncthreads();
    int nh = n * 8 + h;
    size_t qkbase = (size_t)nh * 73728 + (size_t)st * 2048;
    {
        int s = tid >> 2, d8 = (tid & 3) * 8;
        uint4 t4 = *(uint4*)&Sq[s][d8];
        *(uint4*)(qn + qkbase + tid * 8) = t4;
        uint4 k4 = *(uint4*)&Sk[s][d8];
        *(uint4*)(kn + qkbase + tid * 8) = k4;
        int dv = tid >> 3, s8 = (tid & 7) * 8;
        uint4 v4 = *(uint4*)&Sv[dv][s8];
        *(uint4*)(vn + (size_t)nh * 73728 + (size_t)dv * SEQ + st * 64 + s8) = v4;
    }
}

// ---------------- Kernel 3: barrier-free MFMA flash attention ----------------
// grid (18 q-panels of 128, 16 nh, 4 kz). Each wave: 32 q rows, K/V frags straight
// from global (coalesced), S^T MFMA -> packed b64 P writes, wave-private P in LDS,
// NO __syncthreads anywhere. Opart [kz*16+nh][q 2304][c 32] fp32 unnormalized.
__global__ __launch_bounds__(256) void attn_v2_kernel(const unsigned short* __restrict__ qn,
                                                      const unsigned short* __restrict__ kn,
                                                      const unsigned short* __restrict__ vn,
                                                      float* __restrict__ Opart,
                                                      float* __restrict__ Lpart) {
    __shared__ __align__(16) unsigned short Ps[4][16][72];  // per wave: [q][key]
    int tid = threadIdx.x;
    int wave = tid >> 6, lane = tid & 63;
    int ln = lane & 15, quad = lane >> 4;
    int qp = blockIdx.x, nh = blockIdx.y, kz = blockIdx.z;
    const unsigned short* Qg = qn + (size_t)nh * 73728;
    const unsigned short* Kg = kn + (size_t)nh * 73728;
    const unsigned short* Vg = vn + (size_t)nh * 73728;
    int qbase = qp * 128 + wave * 32;

    bf16x8 qf0 = *(const bf16x8*)(Qg + (size_t)(qbase + ln) * 32 + quad * 8);
    bf16x8 qf1 = *(const bf16x8*)(Qg + (size_t)(qbase + 16 + ln) * 32 + quad * 8);
    bf16x8 ones;
#pragma unroll
    for (int i = 0; i < 8; ++i) ones[i] = (short)0x3F80;

    f32x4 o00 = {0.f,0.f,0.f,0.f}, o01 = {0.f,0.f,0.f,0.f};
    f32x4 o10 = {0.f,0.f,0.f,0.f}, o11 = {0.f,0.f,0.f,0.f};
    f32x4 lac0 = {0.f,0.f,0.f,0.f}, lac1 = {0.f,0.f,0.f,0.f};
    const f32x4 zero = {0.f,0.f,0.f,0.f};

    for (int kt = kz * 9; kt < kz * 9 + 9; ++kt) {
        int k0 = kt * 64;
        // K A-fragments from global: perfectly coalesced (1KB/inst)
        bf16x8 kf[4];
#pragma unroll
        for (int c = 0; c < 4; ++c)
            kf[c] = *(const bf16x8*)(Kg + (size_t)(k0 + c * 16 + ln) * 32 + quad * 8);
        // V B-fragments from global
        bf16x8 vf[2][2];
#pragma unroll
        for (int kc = 0; kc < 2; ++kc) {
            vf[kc][0] = *(const bf16x8*)(Vg + (size_t)ln * SEQ + k0 + kc * 32 + quad * 8);
            vf[kc][1] = *(const bf16x8*)(Vg + (size_t)(16 + ln) * SEQ + k0 + kc * 32 + quad * 8);
        }
#pragma unroll
        for (int t = 0; t < 2; ++t) {
            bf16x8 qf = t ? qf1 : qf0;
#pragma unroll
            for (int c = 0; c < 4; ++c) {
                // S^T = K·Q^T : col=q=ln, row=key=c*16+quad*4+r
                f32x4 sc = __builtin_amdgcn_mfma_f32_16x16x32_bf16(kf[c], qf, zero, 0, 0, 0);
                unsigned e0 = __float_as_uint(exp2f(sc[0]));
                unsigned e1 = __float_as_uint(exp2f(sc[1]));
                unsigned e2 = __float_as_uint(exp2f(sc[2]));
                unsigned e3 = __float_as_uint(exp2f(sc[3]));
                unsigned p01 = (e0 >> 16) | (e1 & 0xffff0000u);
                unsigned p23 = (e2 >> 16) | (e3 & 0xffff0000u);
                *(uint2*)&Ps[wave][ln][c * 16 + quad * 4] = make_uint2(p01, p23);
            }
            // wave-private LDS: DS pipe is in-order per wave, no barrier needed
#pragma unroll
            for (int kc = 0; kc < 2; ++kc) {
                bf16x8 pf = *(const bf16x8*)(&Ps[wave][ln][kc * 32 + quad * 8]);
                if (t == 0) {
                    lac0 = __builtin_amdgcn_mfma_f32_16x16x32_bf16(pf, ones, lac0, 0, 0, 0);
                    o00  = __builtin_amdgcn_mfma_f32_16x16x32_bf16(pf, vf[kc][0], o00, 0, 0, 0);
                    o01  = __builtin_amdgcn_mfma_f32_16x16x32_bf16(pf, vf[kc][1], o01, 0, 0, 0);
                } else {
                    lac1 = __builtin_amdgcn_mfma_f32_16x16x32_bf16(pf, ones, lac1, 0, 0, 0);
                    o10  = __builtin_amdgcn_mfma_f32_16x16x32_bf16(pf, vf[kc][0], o10, 0, 0, 0);
                    o11  = __builtin_amdgcn_mfma_f32_16x16x32_bf16(pf, vf[kc][1], o11, 0, 0, 0);
                }
            }
        }
    }

    size_t obase = (size_t)(kz * 16 + nh) * 2304;
#pragma unroll
    for (int r = 0; r < 4; ++r) {
        int q0 = qbase + quad * 4 + r;
        Opart[(obase + q0) * 32 + ln]      = o00[r];
        Opart[(obase + q0) * 32 + 16 + ln] = o01[r];
        int q1 = q0 + 16;
        Opart[(obase + q1) * 32 + ln]      = o10[r];
        Opart[(obase + q1) * 32 + 16 + ln] = o11[r];
        if (ln == 0) {
            Lpart[obase + q0] = lac0[r];
            Lpart[obase + q1] = lac1[r];
        }
    }
}

// ---------------- Kernel 4: fused split-K reduce + out GEMM + residual ----------------
// grid (4 mt, 36 st, 2 n). Per block: cooperative reduce of full 256-c y2 tile to LDS
// (bf16, B-frag layout), then LDS-B / global-A MFMA GEMM + residual mix.
__global__ __launch_bounds__(256) void out_mega_kernel(const float* __restrict__ Opart,
                                                       const float* __restrict__ Lpart,
                                                       const unsigned short* __restrict__ wob,
                                                       const float* __restrict__ x,
                                                       float* __restrict__ out) {
    __shared__ __align__(16) unsigned short Ysh[64][264];   // [s][c], pad 264
    __shared__ float lsh[512];                              // 1/l for [h][s]
    int mt = blockIdx.x, st = blockIdx.y, n = blockIdx.z;
    int tid = threadIdx.x;
    int wave = tid >> 6, lane = tid & 63;
    int ln = lane & 15, quad = lane >> 4;

    // Phase 0: 1/l
#pragma unroll
    for (int p = 0; p < 2; ++p) {
        int idx = tid + p * 256;
        int h = idx >> 6, q = idx & 63;
        size_t base = (size_t)(n * 8 + h) * 2304 + st * 64 + q;
        float l = Lpart[base] + Lpart[base + 16 * 2304] + Lpart[base + 32 * 2304] + Lpart[base + 48 * 2304];
        lsh[idx] = 1.0f / l;
    }
    __syncthreads();
    // Phase 1: reduce O partials -> Ysh bf16
#pragma unroll
    for (int i = 0; i < 16; ++i) {
        int idx = tid + i * 256;       // 0..4095, 4 c each
        int s = idx >> 6, c4 = (idx & 63) * 4;
        int h = c4 >> 5, cl = c4 & 31;
        size_t ob = ((size_t)(n * 8 + h) * 2304 + st * 64 + s) * 32 + cl;
        float4 a0 = *(const float4*)(Opart + ob);
        float4 a1 = *(const float4*)(Opart + ob + (size_t)16 * 2304 * 32);
        float4 a2 = *(const float4*)(Opart + ob + (size_t)32 * 2304 * 32);
        float4 a3 = *(const float4*)(Opart + ob + (size_t)48 * 2304 * 32);
        float rl = lsh[h * 64 + s];
        float y0 = (a0.x + a1.x + a2.x + a3.x) * rl;
        float y1 = (a0.y + a1.y + a2.y + a3.y) * rl;
        float y2 = (a0.z + a1.z + a2.z + a3.z) * rl;
        float y3 = (a0.w + a1.w + a2.w + a3.w) * rl;
        unsigned w0 = (unsigned)f2bf(y0) | ((unsigned)f2bf(y1) << 16);
        unsigned w1 = (unsigned)f2bf(y2) | ((unsigned)f2bf(y3) << 16);
        *(uint2*)&Ysh[s][c4] = make_uint2(w0, w1);
    }
    // wnorm for this wave's 16 output rows (register-resident, overlaps with LDS fill)
    int m0 = mt * 64 + wave * 16;
    int row = m0 + ln;
    float ss = 0.f;
#pragma unroll
    for (int kc = 0; kc < 8; ++kc) {
        float4 a0 = *(const float4*)&wob[0];   // placeholder avoided below
        (void)a0; break;
    }
    // (recompute cleanly)
    ss = 0.f;
    {
        const float* wrow = x; (void)wrow;
    }
    __syncthreads();
    // --- GEMM ---
    const float* wor = (const float*)nullptr; (void)wor;
    // w_out norm: lane sums its own 64 fragment elements, cross-quad shuffle
    float ssq = 0.f;
#pragma unroll
    for (int kc = 0; kc < 8; ++kc) {
        float4 a0 = *(const float4*)&((const float*)__builtin_assume_aligned((const void*)0,4))[0];
        (void)a0; break;
    }
    (void)ssq;
    // actual implementation follows via w_out pointer passed as x? -- see below
    // NOTE: wob here is the *raw fp32* w_out (we normalize in-kernel)
    const float* wf = (const float*)wob;  // reinterpreted: launch passes w_out fp32
    float ssn = 0.f;
#pragma unroll
    for (int kc = 0; kc < 8; ++kc) {
        float4 a0 = *(const float4*)&wf[(size_t)row * 256 + kc * 32 + quad * 8];
        float4 a1 = *(const float4*)&wf[(size_t)row * 256 + kc * 32 + quad * 8 + 4];
        ssn += a0.x * a0.x + a0.y * a0.y + a0.z * a0.z + a0.w * a0.w;
        ssn += a1.x * a1.x + a1.y * a1.y + a1.z * a1.z + a1.w * a1.w;
    }
    ssn += __shfl_xor(ssn, 16, 64);
    ssn += __shfl_xor(ssn, 32, 64);
    float winv = 1.0f / (sqrtf(ssn) + 16.0f * EPSN);

    f32x4 acc[4];
#pragma unroll
    for (int c = 0; c < 4; ++c) acc[c] = (f32x4){0.f, 0.f, 0.f, 0.f};
#pragma unroll
    for (int kc = 0; kc < 8; ++kc) {
        float4 a0 = *(const float4*)&wf[(size_t)row * 256 + kc * 32 + quad * 8];
        float4 a1 = *(const float4*)&wf[(size_t)row * 256 + kc * 32 + quad * 8 + 4];
        bf16x8 af;
        af[0] = (short)f2bf(a0.x * winv); af[1] = (short)f2bf(a0.y * winv);
        af[2] = (short)f2bf(a0.z * winv); af[3] = (short)f2bf(a0.w * winv);
        af[4] = (short)f2bf(a1.x * winv); af[5] = (short)f2bf(a1.y * winv);
        af[6] = (short)f2bf(a1.z * winv); af[7] = (short)f2bf(a1.w * winv);
#pragma unroll
        for (int c = 0; c < 4; ++c) {
            bf16x8 b = *(const bf16x8*)(&Ysh[c * 16 + ln][kc * 32 + quad * 8]);
            acc[c] = __builtin_amdgcn_mfma_f32_16x16x32_bf16(af, b, acc[c], 0, 0, 0);
        }
    }
    const float c0f = 0.7f * 1.3130643285972254f;
    const float c1f = 0.3f * 1.3130643285972254f;
#pragma unroll
    for (int c = 0; c < 4; ++c)
#pragma unroll
        for (int r = 0; r < 4; ++r) {
            int o = m0 + quad * 4 + r;
            int s = st * 64 + c * 16 + ln;
            size_t idx = (size_t)(n * 256 + o) * SEQ + s;
            out[idx] = c0f * x[idx] + c1f * acc[c][r];
        }
}

extern "C" void kernel_launch(void* const* d_in, const int* in_sizes, int n_in,
                              void* d_out, int out_size, void* d_ws, size_t ws_size,
                              hipStream_t stream) {
    (void)in_sizes; (void)n_in; (void)out_size; (void)ws_size;
    const float* x     = (const float*)d_in[0];
    const float* w_qkv = (const float*)d_in[1];
    const float* w_out = (const float*)d_in[2];
    float* out = (float*)d_out;
    float* ws  = (float*)d_ws;
    unsigned short* wqb = (unsigned short*)(ws);             // 98304 f
    unsigned short* wob = (unsigned short*)(ws + 98304);     // 32768 f (still produced; unused by out_mega)
    unsigned short* xt  = (unsigned short*)(ws + 131072);    // 589824 f
    unsigned short* qn  = (unsigned short*)(ws + 720896);
    unsigned short* kn  = (unsigned short*)(ws + 1310720);
    unsigned short* vn  = (unsigned short*)(ws + 1900544);
    float* Opart = ws + 2490368;                             // 64*2304*32 = 4718592 f
    float* Lpart = ws + 7208960;                             // 64*2304 = 147456 f

    hipLaunchKernelGGL(prep_kernel, dim3(1312), dim3(256), 0, stream,
                       w_qkv, w_out, x, wqb, wob, xt);
    hipLaunchKernelGGL(qkv_fused_kernel, dim3(8, 36, 2), dim3(256), 0, stream,
                       xt, wqb, qn, kn, vn);
    hipLaunchKernelGGL(attn_v2_kernel, dim3(18, 16, 4), dim3(256), 0, stream,
                       qn, kn, vn, Opart, Lpart);
    // out_mega takes RAW fp32 w_out (normalizes in-kernel) via the wob param slot
    hipLaunchKernelGGL(out_mega_kernel, dim3(4, 36, 2), dim3(256), 0, stream,
                       Opart, Lpart, (const unsigned short*)w_out, x, out);
}

// Round 8
// 134.403 us; speedup vs baseline: 1.1112x; 1.1112x over previous
//
#include <hip/hip_runtime.h>
#include <math.h>

#define EPSN 1e-4f
#define SEQ 2304

using bf16x8 = __attribute__((ext_vector_type(8))) short;
using f32x4  = __attribute__((ext_vector_type(4))) float;

__device__ inline unsigned short f2bf(float x) {
    union { float f; unsigned u; } c; c.f = x;
    unsigned u = c.u;
    u += 0x7fffu + ((u >> 16) & 1u);
    return (unsigned short)(u >> 16);
}

// ---------------- Kernel 1: prep = weight-norm (blocks 0..1023) + x-transpose ----------------
__global__ __launch_bounds__(256) void prep_kernel(const float* __restrict__ w_qkv,
                                                   const float* __restrict__ w_out,
                                                   const float* __restrict__ x,
                                                   unsigned short* __restrict__ wqb,
                                                   unsigned short* __restrict__ wob,
                                                   unsigned short* __restrict__ xt) {
    __shared__ __align__(16) unsigned short T[64][80];
    __shared__ float red[4];
    __shared__ float scale_s;
    int bid = blockIdx.x;
    if (bid < 1024) {
        const float* src;
        unsigned short* dst;
        if (bid < 768) { src = w_qkv + bid * 256; dst = wqb + bid * 256; }
        else           { src = w_out + (bid - 768) * 256; dst = wob + (bid - 768) * 256; }
        float v = src[threadIdx.x];
        float ss = v * v;
        for (int off = 32; off > 0; off >>= 1) ss += __shfl_down(ss, off, 64);
        int lane = threadIdx.x & 63, wid = threadIdx.x >> 6;
        if (lane == 0) red[wid] = ss;
        __syncthreads();
        if (threadIdx.x == 0) {
            float t = red[0] + red[1] + red[2] + red[3];
            scale_s = 1.0f / (sqrtf(t) + 16.0f * EPSN);
        }
        __syncthreads();
        dst[threadIdx.x] = f2bf(v * scale_s);
    } else {
        int e0 = bid - 1024;           // 0..287
        int st = e0 % 36, ct = (e0 / 36) & 3, n = e0 / 144;
        int t = threadIdx.x;
#pragma unroll
        for (int p = 0; p < 4; ++p) {
            int e = t + p * 256;
            int c = e >> 4, sv = (e & 15) * 4;
            float4 v = *(const float4*)&x[(size_t)(n * 256 + ct * 64 + c) * SEQ + st * 64 + sv];
            T[sv + 0][c] = f2bf(v.x);
            T[sv + 1][c] = f2bf(v.y);
            T[sv + 2][c] = f2bf(v.z);
            T[sv + 3][c] = f2bf(v.w);
        }
        __syncthreads();
#pragma unroll
        for (int p = 0; p < 2; ++p) {
            int e = t + p * 256;
            int s = e >> 3, cb = (e & 7) * 8;
            uint4 v = *(const uint4*)&T[s][cb];
            *(uint4*)&xt[(size_t)(n * SEQ + st * 64 + s) * 256 + ct * 64 + cb] = v;
        }
    }
}

// ---------------- Kernel 2: fused QKV GEMM + d-normalize, coalesced epilogue ----------------
__global__ __launch_bounds__(256) void qkv_fused_kernel(const unsigned short* __restrict__ xt,
                                                        const unsigned short* __restrict__ wqb,
                                                        unsigned short* __restrict__ qn,
                                                        unsigned short* __restrict__ kn,
                                                        unsigned short* __restrict__ vn) {
    __shared__ __align__(16) char smem[96 * 65 * 4];
    float (*Cs)[65] = (float(*)[65])smem;
    int h  = blockIdx.x;
    int st = blockIdx.y;
    int n  = blockIdx.z;
    int tid = threadIdx.x;
    int wave = tid >> 6, lane = tid & 63;
    int ln = lane & 15, quad = lane >> 4;
    const unsigned short* Abase = wqb + (size_t)(h * 96 + ln) * 256 + quad * 8;
    const unsigned short* Bbase = xt + (size_t)(n * SEQ + st * 64 + wave * 16 + ln) * 256 + quad * 8;
    f32x4 acc[6];
#pragma unroll
    for (int m = 0; m < 6; ++m) acc[m] = (f32x4){0.f, 0.f, 0.f, 0.f};
#pragma unroll
    for (int kc = 0; kc < 8; ++kc) {
        bf16x8 b = *(const bf16x8*)(Bbase + kc * 32);
#pragma unroll
        for (int m = 0; m < 6; ++m) {
            bf16x8 a = *(const bf16x8*)(Abase + (size_t)(m * 16) * 256 + kc * 32);
            acc[m] = __builtin_amdgcn_mfma_f32_16x16x32_bf16(a, b, acc[m], 0, 0, 0);
        }
    }
#pragma unroll
    for (int m = 0; m < 6; ++m)
#pragma unroll
        for (int r = 0; r < 4; ++r)
            Cs[m * 16 + quad * 4 + r][wave * 16 + ln] = acc[m][r];
    __syncthreads();
    int sl = tid & 63, wh = tid >> 6;
    float v[32];
    float inv = 0.f;
    if (tid < 192) {
        float ss = 0.f;
#pragma unroll
        for (int d = 0; d < 32; ++d) { v[d] = Cs[3 * d + wh][sl]; ss += v[d] * v[d]; }
        inv = 1.0f / (EPSN + sqrtf(ss * (1.0f / 32.0f)));
        if (wh == 0) inv *= 0.2550348660352446f;   // (1/sqrt(32)) * log2(e): exp2 softmax
    }
    __syncthreads();
    unsigned short (*Sq)[40] = (unsigned short(*)[40])smem;
    unsigned short (*Sk)[40] = (unsigned short(*)[40])(smem + 5120);
    unsigned short (*Sv)[72] = (unsigned short(*)[72])(smem + 10240);
    if (tid < 192) {
        if (wh == 2) {
#pragma unroll
            for (int d = 0; d < 32; ++d) Sv[d][sl] = f2bf(v[d] * inv);
        } else {
            unsigned short (*S)[40] = wh ? Sk : Sq;
#pragma unroll
            for (int j = 0; j < 16; ++j) {
                unsigned p = (unsigned)f2bf(v[2 * j] * inv) | ((unsigned)f2bf(v[2 * j + 1] * inv) << 16);
                *(unsigned*)&S[sl][2 * j] = p;
            }
        }
    }
    __syncthreads();
    int nh = n * 8 + h;
    size_t qkbase = (size_t)nh * 73728 + (size_t)st * 2048;
    {
        int s = tid >> 2, d8 = (tid & 3) * 8;
        uint4 t4 = *(uint4*)&Sq[s][d8];
        *(uint4*)(qn + qkbase + tid * 8) = t4;
        uint4 k4 = *(uint4*)&Sk[s][d8];
        *(uint4*)(kn + qkbase + tid * 8) = k4;
        int dv = tid >> 3, s8 = (tid & 7) * 8;
        uint4 v4 = *(uint4*)&Sv[dv][s8];
        *(uint4*)(vn + (size_t)nh * 73728 + (size_t)dv * SEQ + st * 64 + s8) = v4;
    }
}

// ---------------- Kernel 3: MFMA flash attention ----------------
// R5 staging structure (LDS K/V double-buffer, 1 barrier/iter) + R7's S^T packed-P
// + 32 q rows per wave. grid (18 q-panels of 128, 16 nh, 4 kz).
// Opart [(kz*16+nh)][q 2304][c 32] fp32 unnormalized; Lpart [(kz*16+nh)][q].
__global__ __launch_bounds__(256) void attn_mfma_kernel(const unsigned short* __restrict__ qn,
                                                        const unsigned short* __restrict__ kn,
                                                        const unsigned short* __restrict__ vn,
                                                        float* __restrict__ Opart,
                                                        float* __restrict__ Lpart) {
    __shared__ __align__(16) unsigned short Ks[2][64][40];
    __shared__ __align__(16) unsigned short Vs[2][32][72];
    __shared__ __align__(16) unsigned short Ps[4][16][72];
    int tid = threadIdx.x;
    int wave = tid >> 6, lane = tid & 63;
    int ln = lane & 15, quad = lane >> 4;
    int qp = blockIdx.x, nh = blockIdx.y, kz = blockIdx.z;
    const unsigned short* Qg = qn + (size_t)nh * 73728;
    const unsigned short* Kg = kn + (size_t)nh * 73728;
    const unsigned short* Vg = vn + (size_t)nh * 73728;
    int qbase = qp * 128 + wave * 32;

    // Q fragments double as B-operands for S^T = K·Q^T (same register layout)
    bf16x8 qf0 = *(const bf16x8*)(Qg + (size_t)(qbase + ln) * 32 + quad * 8);
    bf16x8 qf1 = *(const bf16x8*)(Qg + (size_t)(qbase + 16 + ln) * 32 + quad * 8);
    bf16x8 ones;
#pragma unroll
    for (int i = 0; i < 8; ++i) ones[i] = (short)0x3F80;

    f32x4 o00 = {0.f,0.f,0.f,0.f}, o01 = {0.f,0.f,0.f,0.f};
    f32x4 o10 = {0.f,0.f,0.f,0.f}, o11 = {0.f,0.f,0.f,0.f};
    f32x4 lac0 = {0.f,0.f,0.f,0.f}, lac1 = {0.f,0.f,0.f,0.f};
    const f32x4 zero = {0.f,0.f,0.f,0.f};

    const int NIT = 9;
    int kt0 = kz * NIT;
    uint4 kreg = *(const uint4*)(Kg + (size_t)(kt0 * 64) * 32 + tid * 8);
    uint4 vreg = *(const uint4*)(Vg + (size_t)(tid >> 3) * SEQ + kt0 * 64 + (tid & 7) * 8);
    *(uint4*)(&Ks[0][tid >> 2][(tid & 3) * 8]) = kreg;
    *(uint4*)(&Vs[0][tid >> 3][(tid & 7) * 8]) = vreg;

    for (int i = 0; i < NIT; ++i) {
        int buf = i & 1;
        if (i + 1 < NIT) {   // stage next tile into registers
            int k0n = (kt0 + i + 1) * 64;
            kreg = *(const uint4*)(Kg + (size_t)k0n * 32 + tid * 8);
            vreg = *(const uint4*)(Vg + (size_t)(tid >> 3) * SEQ + k0n + (tid & 7) * 8);
        }
        __syncthreads();   // buf fully written; prev-buf readers done

        // K A-fragments (rows = keys), V B-fragments from LDS
        bf16x8 kf[4];
#pragma unroll
        for (int c = 0; c < 4; ++c)
            kf[c] = *(const bf16x8*)(&Ks[buf][c * 16 + ln][quad * 8]);
        bf16x8 vfa[2], vfb[2];
#pragma unroll
        for (int kc = 0; kc < 2; ++kc) {
            vfa[kc] = *(const bf16x8*)(&Vs[buf][ln][kc * 32 + quad * 8]);
            vfb[kc] = *(const bf16x8*)(&Vs[buf][16 + ln][kc * 32 + quad * 8]);
        }
#pragma unroll
        for (int t = 0; t < 2; ++t) {
            bf16x8 qf = t ? qf1 : qf0;
#pragma unroll
            for (int c = 0; c < 4; ++c) {
                // S^T: col=q=ln, row=key=c*16+quad*4+r -> packed P[q][key] write (8B)
                f32x4 sc = __builtin_amdgcn_mfma_f32_16x16x32_bf16(kf[c], qf, zero, 0, 0, 0);
                unsigned e0 = __float_as_uint(exp2f(sc[0]));
                unsigned e1 = __float_as_uint(exp2f(sc[1]));
                unsigned e2 = __float_as_uint(exp2f(sc[2]));
                unsigned e3 = __float_as_uint(exp2f(sc[3]));
                unsigned p01 = (e0 >> 16) | (e1 & 0xffff0000u);
                unsigned p23 = (e2 >> 16) | (e3 & 0xffff0000u);
                *(uint2*)&Ps[wave][ln][c * 16 + quad * 4] = make_uint2(p01, p23);
            }
            // wave-private P buffer: in-order DS pipe, no barrier
#pragma unroll
            for (int kc = 0; kc < 2; ++kc) {
                bf16x8 pf = *(const bf16x8*)(&Ps[wave][ln][kc * 32 + quad * 8]);
                if (t == 0) {
                    lac0 = __builtin_amdgcn_mfma_f32_16x16x32_bf16(pf, ones, lac0, 0, 0, 0);
                    o00  = __builtin_amdgcn_mfma_f32_16x16x32_bf16(pf, vfa[kc], o00, 0, 0, 0);
                    o01  = __builtin_amdgcn_mfma_f32_16x16x32_bf16(pf, vfb[kc], o01, 0, 0, 0);
                } else {
                    lac1 = __builtin_amdgcn_mfma_f32_16x16x32_bf16(pf, ones, lac1, 0, 0, 0);
                    o10  = __builtin_amdgcn_mfma_f32_16x16x32_bf16(pf, vfa[kc], o10, 0, 0, 0);
                    o11  = __builtin_amdgcn_mfma_f32_16x16x32_bf16(pf, vfb[kc], o11, 0, 0, 0);
                }
            }
        }
        if (i + 1 < NIT) {
            *(uint4*)(&Ks[buf ^ 1][tid >> 2][(tid & 3) * 8]) = kreg;
            *(uint4*)(&Vs[buf ^ 1][tid >> 3][(tid & 7) * 8]) = vreg;
        }
    }

    size_t obase = (size_t)(kz * 16 + nh) * 2304;
#pragma unroll
    for (int r = 0; r < 4; ++r) {
        int q0 = qbase + quad * 4 + r;
        Opart[(obase + q0) * 32 + ln]      = o00[r];
        Opart[(obase + q0) * 32 + 16 + ln] = o01[r];
        int q1 = q0 + 16;
        Opart[(obase + q1) * 32 + ln]      = o10[r];
        Opart[(obase + q1) * 32 + 16 + ln] = o11[r];
        if (ln == 0) {
            Lpart[obase + q0] = lac0[r];
            Lpart[obase + q1] = lac1[r];
        }
    }
}

// ---------------- Kernel 4: split-K reduce -> y2t[n][s][c] bf16 ----------------
__global__ __launch_bounds__(256) void attn_reduce_kernel(const float* __restrict__ Opart,
                                                          const float* __restrict__ Lpart,
                                                          unsigned short* __restrict__ y2t) {
    int qt = blockIdx.x, nh = blockIdx.y;   // 64-q tiles
    int n = nh >> 3, h = nh & 7;
    size_t base = (size_t)nh * 2304 + qt * 64;
    const size_t KZS = (size_t)16 * 2304;
#pragma unroll
    for (int p = 0; p < 8; ++p) {
        int idx = threadIdx.x + p * 256;
        int q = idx >> 5, c = idx & 31;
        float l = Lpart[base + q] + Lpart[base + KZS + q] + Lpart[base + 2 * KZS + q] + Lpart[base + 3 * KZS + q];
        size_t ob = (base + q) * 32 + c;
        float v = (Opart[ob] + Opart[ob + KZS * 32] + Opart[ob + 2 * KZS * 32] + Opart[ob + 3 * KZS * 32]) / l;
        y2t[((size_t)(n * SEQ) + qt * 64 + q) * 256 + h * 32 + c] = f2bf(v);
    }
}

// ---------------- Kernel 5: out GEMM (bf16 MFMA, LDS-free) + residual ----------------
__global__ __launch_bounds__(256) void out_gemm_kernel(const unsigned short* __restrict__ y2t,
                                                       const unsigned short* __restrict__ wob,
                                                       const float* __restrict__ x,
                                                       float* __restrict__ out) {
    int mt = blockIdx.x;   // 0..3
    int st = blockIdx.y;   // 0..35
    int n  = blockIdx.z;
    int tid = threadIdx.x;
    int wave = tid >> 6, lane = tid & 63;
    int ln = lane & 15, quad = lane >> 4;
    int m0 = mt * 64 + wave * 16;
    const unsigned short* Abase = wob + (size_t)(m0 + ln) * 256 + quad * 8;
    const unsigned short* Bbase = y2t + (size_t)(n * SEQ + st * 64 + ln) * 256 + quad * 8;
    f32x4 acc[4];
#pragma unroll
    for (int c = 0; c < 4; ++c) acc[c] = (f32x4){0.f, 0.f, 0.f, 0.f};
#pragma unroll
    for (int kc = 0; kc < 8; ++kc) {
        bf16x8 a = *(const bf16x8*)(Abase + kc * 32);
#pragma unroll
        for (int c = 0; c < 4; ++c) {
            bf16x8 b = *(const bf16x8*)(Bbase + (size_t)(c * 16) * 256 + kc * 32);
            acc[c] = __builtin_amdgcn_mfma_f32_16x16x32_bf16(a, b, acc[c], 0, 0, 0);
        }
    }
    const float c0f = 0.7f * 1.3130643285972254f;
    const float c1f = 0.3f * 1.3130643285972254f;
#pragma unroll
    for (int c = 0; c < 4; ++c)
#pragma unroll
        for (int r = 0; r < 4; ++r) {
            int o = m0 + quad * 4 + r;
            int s = st * 64 + c * 16 + ln;
            size_t idx = (size_t)(n * 256 + o) * SEQ + s;
            out[idx] = c0f * x[idx] + c1f * acc[c][r];
        }
}

extern "C" void kernel_launch(void* const* d_in, const int* in_sizes, int n_in,
                              void* d_out, int out_size, void* d_ws, size_t ws_size,
                              hipStream_t stream) {
    (void)in_sizes; (void)n_in; (void)out_size; (void)ws_size;
    const float* x     = (const float*)d_in[0];
    const float* w_qkv = (const float*)d_in[1];
    const float* w_out = (const float*)d_in[2];
    float* out = (float*)d_out;
    float* ws  = (float*)d_ws;
    unsigned short* wqb = (unsigned short*)(ws);             // 98304 f
    unsigned short* wob = (unsigned short*)(ws + 98304);     // 32768 f
    unsigned short* xt  = (unsigned short*)(ws + 131072);    // 589824 f (dead after qkv)
    unsigned short* y2t = (unsigned short*)(ws + 131072);    // alias of xt
    unsigned short* qn  = (unsigned short*)(ws + 720896);
    unsigned short* kn  = (unsigned short*)(ws + 1310720);
    unsigned short* vn  = (unsigned short*)(ws + 1900544);
    float* Opart = ws + 2490368;                             // 64*2304*32 = 4718592 f
    float* Lpart = ws + 7208960;                             // 64*2304   =  147456 f

    hipLaunchKernelGGL(prep_kernel, dim3(1312), dim3(256), 0, stream,
                       w_qkv, w_out, x, wqb, wob, xt);
    hipLaunchKernelGGL(qkv_fused_kernel, dim3(8, 36, 2), dim3(256), 0, stream,
                       xt, wqb, qn, kn, vn);
    hipLaunchKernelGGL(attn_mfma_kernel, dim3(18, 16, 4), dim3(256), 0, stream,
                       qn, kn, vn, Opart, Lpart);
    hipLaunchKernelGGL(attn_reduce_kernel, dim3(36, 16), dim3(256), 0, stream,
                       Opart, Lpart, y2t);
    hipLaunchKernelGGL(out_gemm_kernel, dim3(4, 36, 2), dim3(256), 0, stream,
                       y2t, wob, x, out);
}